// Round 8
// baseline (293.050 us; speedup 1.0000x reference)
//
#include <hip/hip_runtime.h>
#include <math.h>

// Problem dims (fixed)
constexpr int NB  = 8;    // batch
constexpr int NR  = 128;  // rule nodes
constexpr int HID = 256;  // hidden
constexpr int NIN = 512;  // input dim
constexpr int DHD = 64;   // head dim
constexpr size_t SZ = (size_t)NB * NR * HID;  // 262144

struct KP {
    const float *x, *We, *be, *msg_W1, *msg_b1, *msg_W2, *msg_b2;
    const float *upd_W1, *upd_b1, *upd_W2, *upd_b2, *ln_g, *ln_b, *rule_adj;
    const float *Wq, *bq, *Wk, *bk, *Wv, *bv, *Wo, *bo, *ro_W1, *ro_b1, *ro_W2, *ro_b2;
    float* out;
    float *N0, *N1, *N2;                 // normalized h streams
    float *aB, *bbB, *p1B;               // proj set B (layer inputs / qkv)
    float *aA, *bbA, *p1A;               // proj set A
    float *W2u, *mb2u, *Aw, *rsum;       // W2u[l] = msg_W2[l]@upd_W1b[l]
    float *mW1s;                         // layer0: msg_W1a + msg_W1b
    float *h0g, *c0g, *c1g;
    float *gacc;                         // tail mean accumulator [8,256]
    float *scratch;
};

// ---------------------------------------------------------------------------
// 64x64-tile fp32 GEMM core (K=256, BK=16) — used only in setup (W2u).
// ---------------------------------------------------------------------------
__device__ __forceinline__ void gemm_core(
    float (&As)[16][68], float (&Bs)[16][64], int m0, int n0,
    const float* __restrict__ A, const float* __restrict__ B,
    float (&acc)[4][4])
{
    int tid = threadIdx.x;
    int ty = tid >> 4, tx = tid & 15;
    int arow = tid >> 2, acol = (tid & 3) << 2;
    int brow = tid >> 4, bcol = (tid & 15) << 2;
    int m = m0 + arow;

    float4 av = *(const float4*)&A[(size_t)m * HID + acol];
    float4 bv = *(const float4*)&B[(size_t)brow * HID + n0 + bcol];

    for (int k0 = 0; k0 < HID; k0 += 16) {
        As[acol + 0][arow] = av.x;
        As[acol + 1][arow] = av.y;
        As[acol + 2][arow] = av.z;
        As[acol + 3][arow] = av.w;
        *(float4*)&Bs[brow][bcol] = bv;
        __syncthreads();
        if (k0 + 16 < HID) {
            av = *(const float4*)&A[(size_t)m * HID + k0 + 16 + acol];
            bv = *(const float4*)&B[(size_t)(k0 + 16 + brow) * HID + n0 + bcol];
        }
#pragma unroll
        for (int kk = 0; kk < 16; ++kk) {
            float4 af = *(const float4*)&As[kk][ty << 2];
            float4 bf = *(const float4*)&Bs[kk][tx << 2];
            float a_[4] = {af.x, af.y, af.z, af.w};
            float b_[4] = {bf.x, bf.y, bf.z, bf.w};
#pragma unroll
            for (int i = 0; i < 4; ++i)
#pragma unroll
                for (int j = 0; j < 4; ++j) acc[i][j] += a_[i] * b_[j];
        }
        __syncthreads();
    }
}

// ---------------------------------------------------------------------------
// Wave-split GEMV (tail): y[0..255] = act(xs @ W + bias). W row-major [256,256].
// ---------------------------------------------------------------------------
__device__ __forceinline__ void gemv256w(
    const float* xs, const float* __restrict__ W,
    const float* __restrict__ bias, int relu, float* ys, float* red)
{
    int tid = threadIdx.x;
    int w = tid >> 6, l = tid & 63;
    float4 acc = {0.f, 0.f, 0.f, 0.f};
    const float* Wp = W + (size_t)(w * 64) * HID + l * 4;
    const float* xp = xs + w * 64;
#pragma unroll 16
    for (int kk = 0; kk < 64; ++kk) {
        float xv = xp[kk];
        float4 wv = *(const float4*)(Wp + (size_t)kk * HID);
        acc.x += xv * wv.x; acc.y += xv * wv.y;
        acc.z += xv * wv.z; acc.w += xv * wv.w;
    }
    *(float4*)&red[w * 256 + l * 4] = acc;
    __syncthreads();
    float v = red[tid] + red[256 + tid] + red[512 + tid] + red[768 + tid];
    if (bias) v += bias[tid];
    if (relu) v = fmaxf(v, 0.0f);
    ys[tid] = v;
    __syncthreads();
}

// ---------------------------------------------------------------------------
// rows4 @ W: out[ii] = rows[ii][:] dot W[:,n], n = threadIdx.x. W [256,256].
// LDS reads are same-address broadcasts (free); W reads coalesced.
// ---------------------------------------------------------------------------
__device__ __forceinline__ void rows4_matmul(
    const float (&rows)[4][HID], const float* __restrict__ W, int n, float o[4])
{
    o[0] = o[1] = o[2] = o[3] = 0.f;
#pragma unroll 4
    for (int k0 = 0; k0 < HID; k0 += 4) {
        float w0 = W[(size_t)(k0 + 0) * HID + n];
        float w1 = W[(size_t)(k0 + 1) * HID + n];
        float w2 = W[(size_t)(k0 + 2) * HID + n];
        float w3 = W[(size_t)(k0 + 3) * HID + n];
#pragma unroll
        for (int ii = 0; ii < 4; ++ii) {
            float4 rv = *(const float4*)&rows[ii][k0];
            o[ii] += rv.x * w0 + rv.y * w1 + rv.z * w2 + rv.w * w3;
        }
    }
}

// Block-local LN stats: thread holds v[ii] for rows m0+ii at its column.
// Writes mu/inv into mi[4][2] (LDS). Contains two __syncthreads.
__device__ __forceinline__ void ln_stats4_loc(
    float (&sred)[4][4][2], float (&mi)[4][2], const float v[4])
{
    int w = threadIdx.x >> 6, l = threadIdx.x & 63;
    float s[4], q[4];
#pragma unroll
    for (int ii = 0; ii < 4; ++ii) { s[ii] = v[ii]; q[ii] = v[ii] * v[ii]; }
#pragma unroll
    for (int off = 32; off; off >>= 1) {
#pragma unroll
        for (int ii = 0; ii < 4; ++ii) {
            s[ii] += __shfl_xor(s[ii], off);
            q[ii] += __shfl_xor(q[ii], off);
        }
    }
    if (l == 0) {
#pragma unroll
        for (int ii = 0; ii < 4; ++ii) { sred[w][ii][0] = s[ii]; sred[w][ii][1] = q[ii]; }
    }
    __syncthreads();
    if (threadIdx.x < 4) {
        int r = threadIdx.x;
        float ss = sred[0][r][0] + sred[1][r][0] + sred[2][r][0] + sred[3][r][0];
        float qq = sred[0][r][1] + sred[1][r][1] + sred[2][r][1] + sred[3][r][1];
        float mu = ss * (1.0f / HID);
        mi[r][0] = mu;
        mi[r][1] = rsqrtf(qq * (1.0f / HID) - mu * mu + 1e-5f);
    }
    __syncthreads();
}

// ---------------------------------------------------------------------------
// Setup: adjacency | W2u[l]=mW2[l]@uW1b[l] | mb2u | h0 | mW1s | prefetch.
// ---------------------------------------------------------------------------
__global__ __launch_bounds__(256) void setup0_kernel(KP P) {
    __shared__ union {
        struct { float As[16][68]; float Bs[16][64]; } g;
        struct { float xs[NIN]; float part[8][32]; } e;
    } L;
    int blk = blockIdx.x;
    int t = threadIdx.x;

    if (blk < 32) {
        int rr = blk * 4 + (t >> 6);
        int l = t & 63;
        float s_loc = 0.f;
#pragma unroll
        for (int rep = 0; rep < 2; ++rep) {
            int j = l + rep * 64;
            float xv = P.rule_adj[rr * NR + j];
            float sg = 1.0f / (1.0f + expf(-xv));
            if (j == rr) sg = 0.0f;
            P.Aw[rr * NR + j] = sg;
            s_loc += sg;
        }
#pragma unroll
        for (int off = 32; off; off >>= 1) s_loc += __shfl_xor(s_loc, off);
        if (l == 0) P.rsum[rr] = s_loc;
    } else if (blk < 80) {
        int idx = blk - 32, l2 = idx >> 4, t16 = idx & 15;
        int m0 = (t16 >> 2) * 64, n0 = (t16 & 3) * 64;
        float acc[4][4] = {};
        gemm_core(L.g.As, L.g.Bs, m0, n0,
                  P.msg_W2 + (size_t)l2 * HID * HID,
                  P.upd_W1 + (size_t)l2 * 2 * HID * HID + (size_t)HID * HID,
                  acc);
        int ty = t >> 4, tx = t & 15;
        float* C = P.W2u + (size_t)l2 * HID * HID;
#pragma unroll
        for (int i = 0; i < 4; ++i) {
            int m = m0 + (ty << 2) + i, n = n0 + (tx << 2);
            float4 o = {acc[i][0], acc[i][1], acc[i][2], acc[i][3]};
            *(float4*)&C[(size_t)m * HID + n] = o;
        }
    } else if (blk < 83) {
        int l2 = blk - 80;
        const float* b2v = P.msg_b2 + l2 * HID;
        const float* Bm = P.upd_W1 + (size_t)l2 * 2 * HID * HID + (size_t)HID * HID;
        float acc = 0.f;
#pragma unroll 4
        for (int k = 0; k < HID; ++k) acc += b2v[k] * Bm[(size_t)k * HID + t];
        P.mb2u[l2 * HID + t] = acc;
    } else if (blk < 147) {
        // h0[b] = x[b]@We + be, distributed (8 b x 8 col-slices)
        int idx = blk - 83;
        int b = idx >> 3, s = idx & 7;
        L.e.xs[t]       = P.x[b * NIN + t];
        L.e.xs[256 + t] = P.x[b * NIN + 256 + t];
        __syncthreads();
        int c = t & 31, seg = t >> 5;
        int col = s * 32 + c;
        const float* Wp = P.We + (size_t)(seg * 64) * HID + col;
        const float* xp = L.e.xs + seg * 64;
        float acc = 0.f;
#pragma unroll 16
        for (int k = 0; k < 64; ++k) acc += xp[k] * Wp[(size_t)k * HID];
        L.e.part[seg][c] = acc;
        __syncthreads();
        if (t < 32) {
            float v = 0.f;
#pragma unroll
            for (int sg = 0; sg < 8; ++sg) v += L.e.part[sg][t];
            int cc = s * 32 + t;
            P.h0g[b * HID + cc] = v + P.be[cc];
        }
    } else if (blk < 163) {
        int base = (blk - 147) * 4096;
        for (int i = t; i < 4096; i += 256) {
            int o = base + i;
            P.mW1s[o] = P.msg_W1[o] + P.msg_W1[65536 + o];
        }
    } else {
        // prefetch all weights -> warm L3 (poison evicts it every replay)
        int pfid = blk - 163, npf = 256 - 163;
        const float* arr[11] = {P.We, P.msg_W1, P.msg_W2, P.upd_W1, P.upd_W2,
                                P.Wq, P.Wk, P.Wv, P.Wo, P.ro_W1, P.ro_W2};
        const int n4[11] = {32768, 98304, 49152, 98304, 49152,
                            16384, 16384, 16384, 16384, 16384, 8192};
        float s = 0.f;
        for (int a = 0; a < 11; ++a) {
            const float4* p4 = (const float4*)arr[a];
            for (int i = pfid * 256 + t; i < n4[a]; i += npf * 256) {
                float4 v = p4[i];
                s += v.x + v.y + v.z + v.w;
            }
        }
        if (s == 1.0e37f) P.scratch[pfid] = s;  // keeps loads live
    }
}

// ---------------------------------------------------------------------------
// Head chain in one dispatch (grid 128):
//  z=0: c0[b, slice] = h0[b] @ uW1a(0) slice
//  z=1: p0[b] = relu(h0[b]@mW1s + mb1(0)) (redundant per block);
//       c1[b, slice] = p0 @ W2u(0) slice + mb2u(0)
// ---------------------------------------------------------------------------
__global__ __launch_bounds__(256) void headc_kernel(KP P) {
    __shared__ float h0s[HID];
    __shared__ float p0s[HID];
    __shared__ float part[8][32];
    int blk = blockIdx.x;
    int z = blk >> 6, bs = blk & 63;
    int b = bs >> 3, s = bs & 7;
    int t = threadIdx.x;
    h0s[t] = P.h0g[b * HID + t];
    __syncthreads();
    const float* Wslice;
    const float* xs;
    if (z == 0) {
        Wslice = P.upd_W1;
        xs = h0s;
    } else {
        float accp = 0.f;
#pragma unroll 8
        for (int k = 0; k < HID; ++k)
            accp += h0s[k] * P.mW1s[(size_t)k * HID + t];
        p0s[t] = fmaxf(accp + P.msg_b1[t], 0.0f);
        __syncthreads();
        Wslice = P.W2u;
        xs = p0s;
    }
    int c = t & 31, seg = t >> 5;
    int col = s * 32 + c;
    const float* Wp = Wslice + (size_t)(seg * 32) * HID + col;
    const float* xp = xs + seg * 32;
    float acc = 0.f;
#pragma unroll 8
    for (int k = 0; k < 32; ++k) acc += xp[k] * Wp[(size_t)k * HID];
    part[seg][c] = acc;
    __syncthreads();
    if (t < 32) {
        float v = 0.f;
#pragma unroll
        for (int sg = 0; sg < 8; ++sg) v += part[sg][t];
        int cc = s * 32 + t;
        if (z == 0) P.c0g[b * HID + cc] = v;
        else        P.c1g[b * HID + cc] = v + P.mb2u[cc];
    }
}

// ---------------------------------------------------------------------------
// Layer 0 + projection (grid 256, 4 rows/block):
//   u1 = relu(c0[b] + rsum[i]*c1[b] + ub1(0)); u = u1@uW2(0)
//   v = h0[b] + u + ub2(0); N0 = LN0(v)  [block-local stats]
//   proj: a1 = N0@mW1a(1); bb1 = N0@mW1b(1); P1 = N0@uW1a(1)
// ---------------------------------------------------------------------------
__global__ __launch_bounds__(256) void layer0p_kernel(KP P) {
    __shared__ float u1s[4][HID];
    __shared__ float nrm[4][HID];
    __shared__ float sred[4][4][2];
    __shared__ float mi[4][2];
    int blk = blockIdx.x;
    int m0 = blk * 4;
    int b = m0 >> 7, i0 = m0 & 127;
    int t = threadIdx.x;

    float c0v = P.c0g[b * HID + t];
    float c1v = P.c1g[b * HID + t];
    float ubv = P.upd_b1[t];
#pragma unroll
    for (int ii = 0; ii < 4; ++ii)
        u1s[ii][t] = fmaxf(c0v + P.rsum[i0 + ii] * c1v + ubv, 0.0f);
    __syncthreads();

    float u[4];
    rows4_matmul(u1s, P.upd_W2, t, u);

    float h0v = P.h0g[b * HID + t] + P.upd_b2[t];
    float v[4];
#pragma unroll
    for (int ii = 0; ii < 4; ++ii) v[ii] = u[ii] + h0v;

    ln_stats4_loc(sred, mi, v);
    float gv = P.ln_g[t], btv = P.ln_b[t];
#pragma unroll
    for (int ii = 0; ii < 4; ++ii) {
        float nv = (v[ii] - mi[ii][0]) * mi[ii][1] * gv + btv;
        nrm[ii][t] = nv;
        P.N0[(size_t)(m0 + ii) * HID + t] = nv;
    }
    __syncthreads();

    const float* mW1a1 = P.msg_W1 + (size_t)1 * 2 * HID * HID;
    const float* uW1a1 = P.upd_W1 + (size_t)1 * 2 * HID * HID;
    float o[4];
    rows4_matmul(nrm, mW1a1, t, o);
#pragma unroll
    for (int ii = 0; ii < 4; ++ii) P.aB[(size_t)(m0 + ii) * HID + t] = o[ii];
    rows4_matmul(nrm, mW1a1 + (size_t)HID * HID, t, o);
#pragma unroll
    for (int ii = 0; ii < 4; ++ii) P.bbB[(size_t)(m0 + ii) * HID + t] = o[ii];
    rows4_matmul(nrm, uW1a1, t, o);
#pragma unroll
    for (int ii = 0; ii < 4; ++ii) P.p1B[(size_t)(m0 + ii) * HID + t] = o[ii];
}

// ---------------------------------------------------------------------------
// Fused aggregate + u1 + resid + LN + next-layer projection. 4 rows/block.
//   agg = sum_j Aw[i,j]*relu(a_i + bb_j + mb1)
//   u1 = relu(agg@W2u + P1 + rsum*mb2u + ub1); u = u1@uW2
//   v = Nprev + u + ub2; Nout = LN(v)  [block-local]
//   o{0,1,2} = Nout @ pw{0,1,2} (+ pb)
// ---------------------------------------------------------------------------
__global__ __launch_bounds__(256) void aggproj_kernel(
    const float* __restrict__ a, const float* __restrict__ bbv,
    const float* __restrict__ mb1, const float* __restrict__ Aw,
    const float* __restrict__ rsumv,
    const float* __restrict__ P1, const float* __restrict__ W2u,
    const float* __restrict__ mb2u, const float* __restrict__ ub1,
    const float* __restrict__ uW2, const float* __restrict__ ub2,
    const float* __restrict__ Nprev, const float* __restrict__ lng,
    const float* __restrict__ lnb, float* __restrict__ Nout,
    const float* __restrict__ pw0, const float* __restrict__ pb0, float* __restrict__ o0,
    const float* __restrict__ pw1, const float* __restrict__ pb1, float* __restrict__ o1,
    const float* __restrict__ pw2, const float* __restrict__ pb2, float* __restrict__ o2,
    float* __restrict__ gzero)
{
    __shared__ float ap[4][HID];
    __shared__ float u1s[4][HID];
    __shared__ float nrm[4][HID];
    __shared__ float awr[4][NR];
    __shared__ float sred[4][4][2];
    __shared__ float mi[4][2];
    int blk = blockIdx.x;
    int b  = blk >> 5;
    int i0 = (blk & 31) * 4;
    int m0 = b * NR + i0;
    int t  = threadIdx.x;

    if (gzero && blk == 0) {
#pragma unroll
        for (int i = 0; i < 8; ++i) gzero[i * 256 + t] = 0.f;
    }

    if (t < NR) {
#pragma unroll
        for (int ii = 0; ii < 4; ++ii) awr[ii][t] = Aw[(i0 + ii) * NR + t];
    }
    float bias = mb1[t];
    float ai[4];
#pragma unroll
    for (int ii = 0; ii < 4; ++ii)
        ai[ii] = a[(size_t)(m0 + ii) * HID + t] + bias;
    __syncthreads();

    float acc[4] = {0.f, 0.f, 0.f, 0.f};
    const float* bbb = &bbv[(size_t)b * NR * HID + t];
#pragma unroll 4
    for (int j = 0; j < NR; ++j) {
        float bj = bbb[(size_t)j * HID];
#pragma unroll
        for (int ii = 0; ii < 4; ++ii) {
            float pre = fmaxf(ai[ii] + bj, 0.0f);
            acc[ii] += awr[ii][j] * pre;
        }
    }
#pragma unroll
    for (int ii = 0; ii < 4; ++ii) ap[ii][t] = acc[ii];
    __syncthreads();

    float w2[4];
    rows4_matmul(ap, W2u, t, w2);
    float mbv = mb2u[t], ubv = ub1[t];
#pragma unroll
    for (int ii = 0; ii < 4; ++ii) {
        float vv = w2[ii] + P1[(size_t)(m0 + ii) * HID + t] + rsumv[i0 + ii] * mbv + ubv;
        u1s[ii][t] = fmaxf(vv, 0.0f);
    }
    __syncthreads();

    float u[4];
    rows4_matmul(u1s, uW2, t, u);
    float ub2v = ub2[t];
    float v[4];
#pragma unroll
    for (int ii = 0; ii < 4; ++ii)
        v[ii] = Nprev[(size_t)(m0 + ii) * HID + t] + u[ii] + ub2v;

    ln_stats4_loc(sred, mi, v);
    float gv = lng[t], btv = lnb[t];
#pragma unroll
    for (int ii = 0; ii < 4; ++ii) {
        float nv = (v[ii] - mi[ii][0]) * mi[ii][1] * gv + btv;
        nrm[ii][t] = nv;
        Nout[(size_t)(m0 + ii) * HID + t] = nv;
    }
    __syncthreads();

    float o[4];
    rows4_matmul(nrm, pw0, t, o);
    float p0v = pb0 ? pb0[t] : 0.f;
#pragma unroll
    for (int ii = 0; ii < 4; ++ii) o0[(size_t)(m0 + ii) * HID + t] = o[ii] + p0v;
    rows4_matmul(nrm, pw1, t, o);
    float p1v = pb1 ? pb1[t] : 0.f;
#pragma unroll
    for (int ii = 0; ii < 4; ++ii) o1[(size_t)(m0 + ii) * HID + t] = o[ii] + p1v;
    rows4_matmul(nrm, pw2, t, o);
    float p2v = pb2 ? pb2[t] : 0.f;
#pragma unroll
    for (int ii = 0; ii < 4; ++ii) o2[(size_t)(m0 + ii) * HID + t] = o[ii] + p2v;
}

// ---------------------------------------------------------------------------
// Fused attention + mean: blk = bh*8 + ig; 16 q-rows per block, one (b,head).
// ---------------------------------------------------------------------------
__global__ __launch_bounds__(256) void attention_kernel(
    const float* __restrict__ q, const float* __restrict__ k,
    const float* __restrict__ v, float* __restrict__ gacc)
{
    __shared__ struct { float KhT[64][128]; float S[16][128]; float qs[16][64]; } L;
    int blk = blockIdx.x;
    int bh = blk >> 3, ig = blk & 7;
    int b = bh >> 2, hd = bh & 3;
    int i0 = ig * 16;
    int t = threadIdx.x;
    const float* qg = q + ((size_t)b * NR) * HID + hd * DHD;
    const float* kg = k + ((size_t)b * NR) * HID + hd * DHD;
    const float* vg = v + ((size_t)b * NR) * HID + hd * DHD;

    {   // stage K^T
        int j = t >> 1, half = t & 1;
        const float* krow = kg + (size_t)j * HID + half * 32;
#pragma unroll
        for (int c = 0; c < 32; c += 4) {
            float4 kv = *(const float4*)(krow + c);
            L.KhT[half * 32 + c + 0][j] = kv.x;
            L.KhT[half * 32 + c + 1][j] = kv.y;
            L.KhT[half * 32 + c + 2][j] = kv.z;
            L.KhT[half * 32 + c + 3][j] = kv.w;
        }
    }
    {   // stage q rows
        int ii = t >> 4, d0 = (t & 15) * 4;
        *(float4*)&L.qs[ii][d0] = *(const float4*)(qg + (size_t)(i0 + ii) * HID + d0);
    }
    __syncthreads();
    {   // scores
        int j = t & 127, ii2 = t >> 7;
        float acc[8] = {0.f,0.f,0.f,0.f,0.f,0.f,0.f,0.f};
#pragma unroll 4
        for (int d = 0; d < 64; ++d) {
            float kv = L.KhT[d][j];
#pragma unroll
            for (int ii = 0; ii < 8; ++ii) acc[ii] += L.qs[ii2 * 8 + ii][d] * kv;
        }
#pragma unroll
        for (int ii = 0; ii < 8; ++ii) L.S[ii2 * 8 + ii][j] = acc[ii] * 0.125f;
    }
    __syncthreads();
    {   // softmax per row
        int w = t >> 6, l = t & 63;
#pragma unroll
        for (int r = w * 4; r < w * 4 + 4; ++r) {
            float e0 = L.S[r][l], e1 = L.S[r][l + 64];
            float mx = fmaxf(e0, e1);
#pragma unroll
            for (int off = 32; off; off >>= 1) mx = fmaxf(mx, __shfl_xor(mx, off));
            e0 = expf(e0 - mx); e1 = expf(e1 - mx);
            float sm = e0 + e1;
#pragma unroll
            for (int off = 32; off; off >>= 1) sm += __shfl_xor(sm, off);
            float inv = 1.0f / sm;
            L.S[r][l] = e0 * inv; L.S[r][l + 64] = e1 * inv;
        }
    }
    __syncthreads();
    {   // PV + row-sum into gacc
        int d = t & 63, ir = t >> 6;
        float accv[4] = {0.f, 0.f, 0.f, 0.f};
        const float* vp = vg + d;
#pragma unroll 8
        for (int j = 0; j < NR; ++j) {
            float vv = vp[(size_t)j * HID];
#pragma unroll
            for (int p = 0; p < 4; ++p) accv[p] += L.S[p * 4 + ir][j] * vv;
        }
        float s = accv[0] + accv[1] + accv[2] + accv[3];
        atomicAdd(&gacc[b * HID + hd * DHD + d], s);
    }
}

// ---------------------------------------------------------------------------
// Fused tail: per-batch chain. 8 blocks.
// ---------------------------------------------------------------------------
__global__ __launch_bounds__(256) void tailf_kernel(KP P) {
    __shared__ float v0[HID], v1[HID], v2[HID];
    __shared__ float red[1024];
    int b = blockIdx.x;
    int t = threadIdx.x;
    int w = t >> 6, l = t & 63;

    v0[t] = P.gacc[b * HID + t] * (1.0f / NR);
    __syncthreads();
    gemv256w(v0, P.Wo, P.bo, 0, v1, red);
    gemv256w(v1, P.ro_W1, P.ro_b1, 1, v2, red);

    {   // logits: N=128; lane l -> outputs 2l,2l+1; wave w -> K quarter
        float2 acc = {0.f, 0.f};
        const float* Wp = P.ro_W2 + (size_t)(w * 64) * NR + l * 2;
        const float* xp = v2 + w * 64;
#pragma unroll 8
        for (int kk = 0; kk < 64; ++kk) {
            float xv = xp[kk];
            float2 wv = *(const float2*)(Wp + (size_t)kk * NR);
            acc.x += xv * wv.x; acc.y += xv * wv.y;
        }
        *(float2*)&red[w * 128 + l * 2] = acc;
        __syncthreads();
    }
    float logit = -1e30f;
    if (t < NR) logit = red[t] + red[128 + t] + red[256 + t] + red[384 + t] + P.ro_b2[t];
    __syncthreads();
    float m = logit;
#pragma unroll
    for (int off = 32; off; off >>= 1) m = fmaxf(m, __shfl_xor(m, off));
    if (l == 0) red[w] = m;
    __syncthreads();
    m = fmaxf(red[0], red[1]);
    float e = (t < NR) ? expf(logit - m) : 0.0f;
    float ssum = e;
#pragma unroll
    for (int off = 32; off; off >>= 1) ssum += __shfl_xor(ssum, off);
    if (l == 0) red[4 + w] = ssum;
    __syncthreads();
    float tot = red[4] + red[5];
    if (t < NR) P.out[b * NR + t] = e / tot;
}

// ---------------------------------------------------------------------------
extern "C" void kernel_launch(void* const* d_in, const int* in_sizes, int n_in,
                              void* d_out, int out_size, void* d_ws, size_t ws_size,
                              hipStream_t stream)
{
    KP P;
    P.x        = (const float*)d_in[0];
    P.We       = (const float*)d_in[1];
    P.be       = (const float*)d_in[2];
    P.msg_W1   = (const float*)d_in[3];
    P.msg_b1   = (const float*)d_in[4];
    P.msg_W2   = (const float*)d_in[5];
    P.msg_b2   = (const float*)d_in[6];
    P.upd_W1   = (const float*)d_in[7];
    P.upd_b1   = (const float*)d_in[8];
    P.upd_W2   = (const float*)d_in[9];
    P.upd_b2   = (const float*)d_in[10];
    P.ln_g     = (const float*)d_in[11];
    P.ln_b     = (const float*)d_in[12];
    P.rule_adj = (const float*)d_in[13];
    P.Wq       = (const float*)d_in[14];
    P.bq       = (const float*)d_in[15];
    P.Wk       = (const float*)d_in[16];
    P.bk       = (const float*)d_in[17];
    P.Wv       = (const float*)d_in[18];
    P.bv       = (const float*)d_in[19];
    P.Wo       = (const float*)d_in[20];
    P.bo       = (const float*)d_in[21];
    P.ro_W1    = (const float*)d_in[22];
    P.ro_b1    = (const float*)d_in[23];
    P.ro_W2    = (const float*)d_in[24];
    P.ro_b2    = (const float*)d_in[25];
    P.out      = (float*)d_out;

    float* b0 = (float*)d_ws;
    P.N0     = b0;  b0 += SZ;
    P.N1     = b0;  b0 += SZ;
    P.N2     = b0;  b0 += SZ;
    P.aB     = b0;  b0 += SZ;
    P.bbB    = b0;  b0 += SZ;
    P.p1B    = b0;  b0 += SZ;
    P.aA     = b0;  b0 += SZ;
    P.bbA    = b0;  b0 += SZ;
    P.p1A    = b0;  b0 += SZ;
    P.W2u    = b0;  b0 += 3 * HID * HID;
    P.mb2u   = b0;  b0 += 3 * HID;
    P.mW1s   = b0;  b0 += HID * HID;
    P.Aw     = b0;  b0 += NR * NR;
    P.rsum   = b0;  b0 += NR;
    P.h0g    = b0;  b0 += NB * HID;
    P.c0g    = b0;  b0 += NB * HID;
    P.c1g    = b0;  b0 += NB * HID;
    P.gacc   = b0;  b0 += NB * HID;
    P.scratch= b0;  b0 += 256;

    // 1. setup: adj | W2u (3 layers) | mb2u | h0 | mW1s | prefetch
    setup0_kernel<<<dim3(256), 256, 0, stream>>>(P);

    // 2. head chain fused: c0 || (p0 -> c1)
    headc_kernel<<<dim3(128), 256, 0, stream>>>(P);

    // 3. layer 0 + projection to layer-1 inputs (set B)
    layer0p_kernel<<<dim3(256), 256, 0, stream>>>(P);

    // 4. layer 1: agg + resid + LN + projection to layer-2 inputs (set A)
    {
        const int l = 1;
        const float* mW1a2 = P.msg_W1 + (size_t)2 * 2 * HID * HID;
        const float* uW1a2 = P.upd_W1 + (size_t)2 * 2 * HID * HID;
        aggproj_kernel<<<dim3(256), 256, 0, stream>>>(
            P.aB, P.bbB, P.msg_b1 + (size_t)l * HID, P.Aw, P.rsum,
            P.p1B, P.W2u + (size_t)l * HID * HID, P.mb2u + l * HID,
            P.upd_b1 + (size_t)l * HID,
            P.upd_W2 + (size_t)l * HID * HID, P.upd_b2 + (size_t)l * HID,
            P.N0, P.ln_g + (size_t)l * HID, P.ln_b + (size_t)l * HID, P.N1,
            mW1a2, nullptr, P.aA,
            mW1a2 + (size_t)HID * HID, nullptr, P.bbA,
            uW1a2, nullptr, P.p1A,
            nullptr);
    }

    // 5. layer 2: agg + resid + LN + projection to q/k/v (set B)
    {
        const int l = 2;
        aggproj_kernel<<<dim3(256), 256, 0, stream>>>(
            P.aA, P.bbA, P.msg_b1 + (size_t)l * HID, P.Aw, P.rsum,
            P.p1A, P.W2u + (size_t)l * HID * HID, P.mb2u + l * HID,
            P.upd_b1 + (size_t)l * HID,
            P.upd_W2 + (size_t)l * HID * HID, P.upd_b2 + (size_t)l * HID,
            P.N1, P.ln_g + (size_t)l * HID, P.ln_b + (size_t)l * HID, P.N2,
            P.Wq, P.bq, P.aB,
            P.Wk, P.bk, P.bbB,
            P.Wv, P.bv, P.p1B,
            P.gacc);
    }

    // 6. attention + mean (atomic into gacc)
    attention_kernel<<<dim3(256), 256, 0, stream>>>(P.aB, P.bbB, P.p1B, P.gacc);

    // 7. fused tail
    tailf_kernel<<<dim3(8), 256, 0, stream>>>(P);
}

// Round 9
// 258.618 us; speedup vs baseline: 1.1331x; 1.1331x over previous
//
#include <hip/hip_runtime.h>
#include <math.h>

// Problem dims (fixed)
constexpr int NB  = 8;    // batch
constexpr int NR  = 128;  // rule nodes
constexpr int HID = 256;  // hidden
constexpr int NIN = 512;  // input dim
constexpr int DHD = 64;   // head dim
constexpr size_t SZ = (size_t)NB * NR * HID;  // 262144

struct KP {
    const float *x, *We, *be, *msg_W1, *msg_b1, *msg_W2, *msg_b2;
    const float *upd_W1, *upd_b1, *upd_W2, *upd_b2, *ln_g, *ln_b, *rule_adj;
    const float *Wq, *bq, *Wk, *bk, *Wv, *bv, *Wo, *bo, *ro_W1, *ro_b1, *ro_W2, *ro_b2;
    float* out;
    float *N0, *N1, *N2;                 // normalized h streams
    float *aB, *bbB, *p1B;               // proj set B (layer inputs / qkv)
    float *aA, *bbA, *p1A;               // proj set A
    float *W2u, *mb2u, *Aw, *rsum;       // W2u[l] = msg_W2[l]@upd_W1b[l]
    float *mW1s;                         // layer0: msg_W1a + msg_W1b
    float *h0g, *c0g, *c1g;
    float *gacc;                         // tail mean accumulator [8,256]
    float *scratch;
};

// ---------------------------------------------------------------------------
// 64x64-tile fp32 GEMM core (K=256, BK=16) — used only in setup (W2u).
// ---------------------------------------------------------------------------
__device__ __forceinline__ void gemm_core(
    float (&As)[16][68], float (&Bs)[16][64], int m0, int n0,
    const float* __restrict__ A, const float* __restrict__ B,
    float (&acc)[4][4])
{
    int tid = threadIdx.x;
    int ty = tid >> 4, tx = tid & 15;
    int arow = tid >> 2, acol = (tid & 3) << 2;
    int brow = tid >> 4, bcol = (tid & 15) << 2;
    int m = m0 + arow;

    float4 av = *(const float4*)&A[(size_t)m * HID + acol];
    float4 bv = *(const float4*)&B[(size_t)brow * HID + n0 + bcol];

    for (int k0 = 0; k0 < HID; k0 += 16) {
        As[acol + 0][arow] = av.x;
        As[acol + 1][arow] = av.y;
        As[acol + 2][arow] = av.z;
        As[acol + 3][arow] = av.w;
        *(float4*)&Bs[brow][bcol] = bv;
        __syncthreads();
        if (k0 + 16 < HID) {
            av = *(const float4*)&A[(size_t)m * HID + k0 + 16 + acol];
            bv = *(const float4*)&B[(size_t)(k0 + 16 + brow) * HID + n0 + bcol];
        }
#pragma unroll
        for (int kk = 0; kk < 16; ++kk) {
            float4 af = *(const float4*)&As[kk][ty << 2];
            float4 bf = *(const float4*)&Bs[kk][tx << 2];
            float a_[4] = {af.x, af.y, af.z, af.w};
            float b_[4] = {bf.x, bf.y, bf.z, bf.w};
#pragma unroll
            for (int i = 0; i < 4; ++i)
#pragma unroll
                for (int j = 0; j < 4; ++j) acc[i][j] += a_[i] * b_[j];
        }
        __syncthreads();
    }
}

// ---------------------------------------------------------------------------
// Wave-split GEMV (tail): y[0..255] = act(xs @ W + bias). W row-major [256,256].
// ---------------------------------------------------------------------------
__device__ __forceinline__ void gemv256w(
    const float* xs, const float* __restrict__ W,
    const float* __restrict__ bias, int relu, float* ys, float* red)
{
    int tid = threadIdx.x;
    int w = tid >> 6, l = tid & 63;
    float4 acc = {0.f, 0.f, 0.f, 0.f};
    const float* Wp = W + (size_t)(w * 64) * HID + l * 4;
    const float* xp = xs + w * 64;
#pragma unroll 16
    for (int kk = 0; kk < 64; ++kk) {
        float xv = xp[kk];
        float4 wv = *(const float4*)(Wp + (size_t)kk * HID);
        acc.x += xv * wv.x; acc.y += xv * wv.y;
        acc.z += xv * wv.z; acc.w += xv * wv.w;
    }
    *(float4*)&red[w * 256 + l * 4] = acc;
    __syncthreads();
    float v = red[tid] + red[256 + tid] + red[512 + tid] + red[768 + tid];
    if (bias) v += bias[tid];
    if (relu) v = fmaxf(v, 0.0f);
    ys[tid] = v;
    __syncthreads();
}

// ---------------------------------------------------------------------------
// 512-thread k-split rows4 partial: col = t&255, half = t>>8.
// Partial o[ii] over k in [half*128, half*128+128). LDS row reads broadcast.
// ---------------------------------------------------------------------------
__device__ __forceinline__ void rows4_half(
    const float (&rows)[4][HID], const float* __restrict__ W,
    int col, int half, float o[4])
{
    o[0] = o[1] = o[2] = o[3] = 0.f;
    int kbase = half * 128;
#pragma unroll 4
    for (int k0 = 0; k0 < 128; k0 += 4) {
        int k = kbase + k0;
        float w0 = W[(size_t)(k + 0) * HID + col];
        float w1 = W[(size_t)(k + 1) * HID + col];
        float w2 = W[(size_t)(k + 2) * HID + col];
        float w3 = W[(size_t)(k + 3) * HID + col];
#pragma unroll
        for (int ii = 0; ii < 4; ++ii) {
            float4 rv = *(const float4*)&rows[ii][k];
            o[ii] += rv.x * w0 + rv.y * w1 + rv.z * w2 + rv.w * w3;
        }
    }
}

// LN stats over half-0 threads (cols 0..255); mu/inv -> mi[4][2].
__device__ __forceinline__ void ln_stats4_512(
    float (&sred)[4][4][2], float (&mi)[4][2], const float v[4], int half)
{
    if (half == 0) {
        int w = threadIdx.x >> 6, l = threadIdx.x & 63;
        float s[4], q[4];
#pragma unroll
        for (int ii = 0; ii < 4; ++ii) { s[ii] = v[ii]; q[ii] = v[ii] * v[ii]; }
#pragma unroll
        for (int off = 32; off; off >>= 1) {
#pragma unroll
            for (int ii = 0; ii < 4; ++ii) {
                s[ii] += __shfl_xor(s[ii], off);
                q[ii] += __shfl_xor(q[ii], off);
            }
        }
        if (l == 0) {
#pragma unroll
            for (int ii = 0; ii < 4; ++ii) { sred[w][ii][0] = s[ii]; sred[w][ii][1] = q[ii]; }
        }
    }
    __syncthreads();
    if (threadIdx.x < 4) {
        int r = threadIdx.x;
        float ss = sred[0][r][0] + sred[1][r][0] + sred[2][r][0] + sred[3][r][0];
        float qq = sred[0][r][1] + sred[1][r][1] + sred[2][r][1] + sred[3][r][1];
        float mu = ss * (1.0f / HID);
        mi[r][0] = mu;
        mi[r][1] = rsqrtf(qq * (1.0f / HID) - mu * mu + 1e-5f);
    }
    __syncthreads();
}

// ---------------------------------------------------------------------------
// Setup: adjacency | W2u[l]=mW2[l]@uW1b[l] | mb2u | h0 | mW1s | prefetch.
// ---------------------------------------------------------------------------
__global__ __launch_bounds__(256) void setup0_kernel(KP P) {
    __shared__ union {
        struct { float As[16][68]; float Bs[16][64]; } g;
        struct { float xs[NIN]; float part[8][32]; } e;
    } L;
    int blk = blockIdx.x;
    int t = threadIdx.x;

    if (blk < 32) {
        int rr = blk * 4 + (t >> 6);
        int l = t & 63;
        float s_loc = 0.f;
#pragma unroll
        for (int rep = 0; rep < 2; ++rep) {
            int j = l + rep * 64;
            float xv = P.rule_adj[rr * NR + j];
            float sg = 1.0f / (1.0f + expf(-xv));
            if (j == rr) sg = 0.0f;
            P.Aw[rr * NR + j] = sg;
            s_loc += sg;
        }
#pragma unroll
        for (int off = 32; off; off >>= 1) s_loc += __shfl_xor(s_loc, off);
        if (l == 0) P.rsum[rr] = s_loc;
    } else if (blk < 80) {
        int idx = blk - 32, l2 = idx >> 4, t16 = idx & 15;
        int m0 = (t16 >> 2) * 64, n0 = (t16 & 3) * 64;
        float acc[4][4] = {};
        gemm_core(L.g.As, L.g.Bs, m0, n0,
                  P.msg_W2 + (size_t)l2 * HID * HID,
                  P.upd_W1 + (size_t)l2 * 2 * HID * HID + (size_t)HID * HID,
                  acc);
        int ty = t >> 4, tx = t & 15;
        float* C = P.W2u + (size_t)l2 * HID * HID;
#pragma unroll
        for (int i = 0; i < 4; ++i) {
            int m = m0 + (ty << 2) + i, n = n0 + (tx << 2);
            float4 o = {acc[i][0], acc[i][1], acc[i][2], acc[i][3]};
            *(float4*)&C[(size_t)m * HID + n] = o;
        }
    } else if (blk < 83) {
        int l2 = blk - 80;
        const float* b2v = P.msg_b2 + l2 * HID;
        const float* Bm = P.upd_W1 + (size_t)l2 * 2 * HID * HID + (size_t)HID * HID;
        float acc = 0.f;
#pragma unroll 4
        for (int k = 0; k < HID; ++k) acc += b2v[k] * Bm[(size_t)k * HID + t];
        P.mb2u[l2 * HID + t] = acc;
    } else if (blk < 147) {
        // h0[b] = x[b]@We + be, distributed (8 b x 8 col-slices)
        int idx = blk - 83;
        int b = idx >> 3, s = idx & 7;
        L.e.xs[t]       = P.x[b * NIN + t];
        L.e.xs[256 + t] = P.x[b * NIN + 256 + t];
        __syncthreads();
        int c = t & 31, seg = t >> 5;
        int col = s * 32 + c;
        const float* Wp = P.We + (size_t)(seg * 64) * HID + col;
        const float* xp = L.e.xs + seg * 64;
        float acc = 0.f;
#pragma unroll 16
        for (int k = 0; k < 64; ++k) acc += xp[k] * Wp[(size_t)k * HID];
        L.e.part[seg][c] = acc;
        __syncthreads();
        if (t < 32) {
            float v = 0.f;
#pragma unroll
            for (int sg = 0; sg < 8; ++sg) v += L.e.part[sg][t];
            int cc = s * 32 + t;
            P.h0g[b * HID + cc] = v + P.be[cc];
        }
    } else if (blk < 163) {
        int base = (blk - 147) * 4096;
        for (int i = t; i < 4096; i += 256) {
            int o = base + i;
            P.mW1s[o] = P.msg_W1[o] + P.msg_W1[65536 + o];
        }
    } else {
        // prefetch all weights -> warm L3 (poison evicts it every replay)
        int pfid = blk - 163, npf = 256 - 163;
        const float* arr[11] = {P.We, P.msg_W1, P.msg_W2, P.upd_W1, P.upd_W2,
                                P.Wq, P.Wk, P.Wv, P.Wo, P.ro_W1, P.ro_W2};
        const int n4[11] = {32768, 98304, 49152, 98304, 49152,
                            16384, 16384, 16384, 16384, 16384, 8192};
        float s = 0.f;
        for (int a = 0; a < 11; ++a) {
            const float4* p4 = (const float4*)arr[a];
            for (int i = pfid * 256 + t; i < n4[a]; i += npf * 256) {
                float4 v = p4[i];
                s += v.x + v.y + v.z + v.w;
            }
        }
        if (s == 1.0e37f) P.scratch[pfid] = s;  // keeps loads live
    }
}

// ---------------------------------------------------------------------------
// Head chain in one dispatch (grid 128):
//  z=0: c0[b, slice] = h0[b] @ uW1a(0) slice
//  z=1: p0[b] = relu(h0[b]@mW1s + mb1(0)) (redundant per block);
//       c1[b, slice] = p0 @ W2u(0) slice + mb2u(0)
// ---------------------------------------------------------------------------
__global__ __launch_bounds__(256) void headc_kernel(KP P) {
    __shared__ float h0s[HID];
    __shared__ float p0s[HID];
    __shared__ float part[8][32];
    int blk = blockIdx.x;
    int z = blk >> 6, bs = blk & 63;
    int b = bs >> 3, s = bs & 7;
    int t = threadIdx.x;
    h0s[t] = P.h0g[b * HID + t];
    __syncthreads();
    const float* Wslice;
    const float* xs;
    if (z == 0) {
        Wslice = P.upd_W1;
        xs = h0s;
    } else {
        float accp = 0.f;
#pragma unroll 8
        for (int k = 0; k < HID; ++k)
            accp += h0s[k] * P.mW1s[(size_t)k * HID + t];
        p0s[t] = fmaxf(accp + P.msg_b1[t], 0.0f);
        __syncthreads();
        Wslice = P.W2u;
        xs = p0s;
    }
    int c = t & 31, seg = t >> 5;
    int col = s * 32 + c;
    const float* Wp = Wslice + (size_t)(seg * 32) * HID + col;
    const float* xp = xs + seg * 32;
    float acc = 0.f;
#pragma unroll 8
    for (int k = 0; k < 32; ++k) acc += xp[k] * Wp[(size_t)k * HID];
    part[seg][c] = acc;
    __syncthreads();
    if (t < 32) {
        float v = 0.f;
#pragma unroll
        for (int sg = 0; sg < 8; ++sg) v += part[sg][t];
        int cc = s * 32 + t;
        if (z == 0) P.c0g[b * HID + cc] = v;
        else        P.c1g[b * HID + cc] = v + P.mb2u[cc];
    }
}

// ---------------------------------------------------------------------------
// Layer 0 + projection. 512 threads (col, k-half), grid 256 (4 rows/block).
// ---------------------------------------------------------------------------
__global__ __launch_bounds__(512) void layer0p_kernel(KP P) {
    __shared__ float u1s[4][HID];
    __shared__ float nrm[4][HID];
    __shared__ float part[2][4][HID];
    __shared__ float sred[4][4][2];
    __shared__ float mi[4][2];
    int blk = blockIdx.x;
    int m0 = blk * 4;
    int b = m0 >> 7, i0 = m0 & 127;
    int t = threadIdx.x;
    int col = t & 255, half = t >> 8;

    if (half == 0) {
        float c0v = P.c0g[b * HID + col];
        float c1v = P.c1g[b * HID + col];
        float ubv = P.upd_b1[col];
#pragma unroll
        for (int ii = 0; ii < 4; ++ii)
            u1s[ii][col] = fmaxf(c0v + P.rsum[i0 + ii] * c1v + ubv, 0.0f);
    }
    __syncthreads();

    float o[4], u[4];
    rows4_half(u1s, P.upd_W2, col, half, o);
#pragma unroll
    for (int ii = 0; ii < 4; ++ii) part[half][ii][col] = o[ii];
    __syncthreads();
#pragma unroll
    for (int ii = 0; ii < 4; ++ii) u[ii] = part[0][ii][col] + part[1][ii][col];

    float v[4] = {0.f, 0.f, 0.f, 0.f};
    if (half == 0) {
        float h0v = P.h0g[b * HID + col] + P.upd_b2[col];
#pragma unroll
        for (int ii = 0; ii < 4; ++ii) v[ii] = u[ii] + h0v;
    }
    ln_stats4_512(sred, mi, v, half);   // first sync also fences part reuse
    if (half == 0) {
        float gv = P.ln_g[col], btv = P.ln_b[col];
#pragma unroll
        for (int ii = 0; ii < 4; ++ii) {
            float nv = (v[ii] - mi[ii][0]) * mi[ii][1] * gv + btv;
            nrm[ii][col] = nv;
            P.N0[(size_t)(m0 + ii) * HID + col] = nv;
        }
    }
    __syncthreads();

    const float* mW1a1 = P.msg_W1 + (size_t)1 * 2 * HID * HID;
    const float* uW1a1 = P.upd_W1 + (size_t)1 * 2 * HID * HID;
    const float* pw[3] = {mW1a1, mW1a1 + (size_t)HID * HID, uW1a1};
    float* po[3] = {P.aB, P.bbB, P.p1B};
#pragma unroll
    for (int p = 0; p < 3; ++p) {
        rows4_half(nrm, pw[p], col, half, o);
#pragma unroll
        for (int ii = 0; ii < 4; ++ii) part[half][ii][col] = o[ii];
        __syncthreads();
        if (half == 0) {
#pragma unroll
            for (int ii = 0; ii < 4; ++ii)
                po[p][(size_t)(m0 + ii) * HID + col] = part[0][ii][col] + part[1][ii][col];
        }
        __syncthreads();
    }
}

// ---------------------------------------------------------------------------
// Fused aggregate + u1 + resid + LN + next-layer projection.
// 512 threads (col, half), grid 256 (4 rows/block). j- and k-split by half.
// ---------------------------------------------------------------------------
__global__ __launch_bounds__(512) void aggproj_kernel(
    const float* __restrict__ a, const float* __restrict__ bbv,
    const float* __restrict__ mb1, const float* __restrict__ Aw,
    const float* __restrict__ rsumv,
    const float* __restrict__ P1, const float* __restrict__ W2u,
    const float* __restrict__ mb2u, const float* __restrict__ ub1,
    const float* __restrict__ uW2, const float* __restrict__ ub2,
    const float* __restrict__ Nprev, const float* __restrict__ lng,
    const float* __restrict__ lnb, float* __restrict__ Nout,
    const float* __restrict__ pw0, const float* __restrict__ pb0, float* __restrict__ o0,
    const float* __restrict__ pw1, const float* __restrict__ pb1, float* __restrict__ o1,
    const float* __restrict__ pw2, const float* __restrict__ pb2, float* __restrict__ o2,
    float* __restrict__ gzero)
{
    __shared__ float ap[4][HID];
    __shared__ float u1s[4][HID];
    __shared__ float nrm[4][HID];
    __shared__ float awr[4][NR];
    __shared__ float part[2][4][HID];
    __shared__ float sred[4][4][2];
    __shared__ float mi[4][2];
    int blk = blockIdx.x;
    int b  = blk >> 5;
    int i0 = (blk & 31) * 4;
    int m0 = b * NR + i0;
    int t  = threadIdx.x;
    int col = t & 255, half = t >> 8;

    if (gzero && blk == 0 && half == 0) {
#pragma unroll
        for (int i = 0; i < 8; ++i) gzero[i * 256 + col] = 0.f;
    }

    // stage adjacency rows: 512 threads cover 4x128 exactly
    awr[t >> 7][t & 127] = Aw[(i0 + (t >> 7)) * NR + (t & 127)];

    float bias = mb1[col];
    float ai[4];
#pragma unroll
    for (int ii = 0; ii < 4; ++ii)
        ai[ii] = a[(size_t)(m0 + ii) * HID + col] + bias;
    __syncthreads();

    // aggregate, j-split: half h sums j in [h*64, h*64+64)
    {
        float acc[4] = {0.f, 0.f, 0.f, 0.f};
        const float* bbb = &bbv[(size_t)b * NR * HID + col];
        int jb = half * 64;
#pragma unroll 4
        for (int j = 0; j < 64; ++j) {
            float bj = bbb[(size_t)(jb + j) * HID];
#pragma unroll
            for (int ii = 0; ii < 4; ++ii) {
                float pre = fmaxf(ai[ii] + bj, 0.0f);
                acc[ii] += awr[ii][jb + j] * pre;
            }
        }
#pragma unroll
        for (int ii = 0; ii < 4; ++ii) part[half][ii][col] = acc[ii];
        __syncthreads();
        if (half == 0) {
#pragma unroll
            for (int ii = 0; ii < 4; ++ii)
                ap[ii][col] = part[0][ii][col] + part[1][ii][col];
        }
        __syncthreads();
    }

    // u1 = relu(ap@W2u + P1 + rsum*mb2u + ub1)   (k-split)
    {
        float o[4];
        rows4_half(ap, W2u, col, half, o);
#pragma unroll
        for (int ii = 0; ii < 4; ++ii) part[half][ii][col] = o[ii];
        __syncthreads();
        if (half == 0) {
            float mbv = mb2u[col], ubv = ub1[col];
#pragma unroll
            for (int ii = 0; ii < 4; ++ii) {
                float w2f = part[0][ii][col] + part[1][ii][col];
                float vv = w2f + P1[(size_t)(m0 + ii) * HID + col]
                         + rsumv[i0 + ii] * mbv + ubv;
                u1s[ii][col] = fmaxf(vv, 0.0f);
            }
        }
        __syncthreads();
    }

    // u = u1s@uW2 ; v = Nprev + u + ub2 ; LN -> nrm, Nout
    {
        float o[4];
        rows4_half(u1s, uW2, col, half, o);
#pragma unroll
        for (int ii = 0; ii < 4; ++ii) part[half][ii][col] = o[ii];
        __syncthreads();
        float v[4] = {0.f, 0.f, 0.f, 0.f};
        if (half == 0) {
            float ub2v = ub2[col];
#pragma unroll
            for (int ii = 0; ii < 4; ++ii) {
                float uf = part[0][ii][col] + part[1][ii][col];
                v[ii] = Nprev[(size_t)(m0 + ii) * HID + col] + uf + ub2v;
            }
        }
        ln_stats4_512(sred, mi, v, half);
        if (half == 0) {
            float gv = lng[col], btv = lnb[col];
#pragma unroll
            for (int ii = 0; ii < 4; ++ii) {
                float nv = (v[ii] - mi[ii][0]) * mi[ii][1] * gv + btv;
                nrm[ii][col] = nv;
                Nout[(size_t)(m0 + ii) * HID + col] = nv;
            }
        }
        __syncthreads();
    }

    // three projections (k-split)
    {
        const float* pw[3] = {pw0, pw1, pw2};
        const float* pb[3] = {pb0, pb1, pb2};
        float* po[3] = {o0, o1, o2};
#pragma unroll
        for (int p = 0; p < 3; ++p) {
            float o[4];
            rows4_half(nrm, pw[p], col, half, o);
#pragma unroll
            for (int ii = 0; ii < 4; ++ii) part[half][ii][col] = o[ii];
            __syncthreads();
            if (half == 0) {
                float pbv = pb[p] ? pb[p][col] : 0.f;
#pragma unroll
                for (int ii = 0; ii < 4; ++ii)
                    po[p][(size_t)(m0 + ii) * HID + col] =
                        part[0][ii][col] + part[1][ii][col] + pbv;
            }
            __syncthreads();
        }
    }
}

// ---------------------------------------------------------------------------
// Fused attention + mean: blk = bh*8 + ig; 16 q-rows per block, one (b,head).
// ---------------------------------------------------------------------------
__global__ __launch_bounds__(256) void attention_kernel(
    const float* __restrict__ q, const float* __restrict__ k,
    const float* __restrict__ v, float* __restrict__ gacc)
{
    __shared__ struct { float KhT[64][128]; float S[16][128]; float qs[16][64]; } L;
    int blk = blockIdx.x;
    int bh = blk >> 3, ig = blk & 7;
    int b = bh >> 2, hd = bh & 3;
    int i0 = ig * 16;
    int t = threadIdx.x;
    const float* qg = q + ((size_t)b * NR) * HID + hd * DHD;
    const float* kg = k + ((size_t)b * NR) * HID + hd * DHD;
    const float* vg = v + ((size_t)b * NR) * HID + hd * DHD;

    {   // stage K^T
        int j = t >> 1, half = t & 1;
        const float* krow = kg + (size_t)j * HID + half * 32;
#pragma unroll
        for (int c = 0; c < 32; c += 4) {
            float4 kv = *(const float4*)(krow + c);
            L.KhT[half * 32 + c + 0][j] = kv.x;
            L.KhT[half * 32 + c + 1][j] = kv.y;
            L.KhT[half * 32 + c + 2][j] = kv.z;
            L.KhT[half * 32 + c + 3][j] = kv.w;
        }
    }
    {   // stage q rows
        int ii = t >> 4, d0 = (t & 15) * 4;
        *(float4*)&L.qs[ii][d0] = *(const float4*)(qg + (size_t)(i0 + ii) * HID + d0);
    }
    __syncthreads();
    {   // scores
        int j = t & 127, ii2 = t >> 7;
        float acc[8] = {0.f,0.f,0.f,0.f,0.f,0.f,0.f,0.f};
#pragma unroll 4
        for (int d = 0; d < 64; ++d) {
            float kv = L.KhT[d][j];
#pragma unroll
            for (int ii = 0; ii < 8; ++ii) acc[ii] += L.qs[ii2 * 8 + ii][d] * kv;
        }
#pragma unroll
        for (int ii = 0; ii < 8; ++ii) L.S[ii2 * 8 + ii][j] = acc[ii] * 0.125f;
    }
    __syncthreads();
    {   // softmax per row
        int w = t >> 6, l = t & 63;
#pragma unroll
        for (int r = w * 4; r < w * 4 + 4; ++r) {
            float e0 = L.S[r][l], e1 = L.S[r][l + 64];
            float mx = fmaxf(e0, e1);
#pragma unroll
            for (int off = 32; off; off >>= 1) mx = fmaxf(mx, __shfl_xor(mx, off));
            e0 = expf(e0 - mx); e1 = expf(e1 - mx);
            float sm = e0 + e1;
#pragma unroll
            for (int off = 32; off; off >>= 1) sm += __shfl_xor(sm, off);
            float inv = 1.0f / sm;
            L.S[r][l] = e0 * inv; L.S[r][l + 64] = e1 * inv;
        }
    }
    __syncthreads();
    {   // PV + row-sum into gacc
        int d = t & 63, ir = t >> 6;
        float accv[4] = {0.f, 0.f, 0.f, 0.f};
        const float* vp = vg + d;
#pragma unroll 8
        for (int j = 0; j < NR; ++j) {
            float vv = vp[(size_t)j * HID];
#pragma unroll
            for (int p = 0; p < 4; ++p) accv[p] += L.S[p * 4 + ir][j] * vv;
        }
        float s = accv[0] + accv[1] + accv[2] + accv[3];
        atomicAdd(&gacc[b * HID + hd * DHD + d], s);
    }
}

// ---------------------------------------------------------------------------
// Fused tail: per-batch chain. 8 blocks.
// ---------------------------------------------------------------------------
__global__ __launch_bounds__(256) void tailf_kernel(KP P) {
    __shared__ float v0[HID], v1[HID], v2[HID];
    __shared__ float red[1024];
    int b = blockIdx.x;
    int t = threadIdx.x;
    int w = t >> 6, l = t & 63;

    v0[t] = P.gacc[b * HID + t] * (1.0f / NR);
    __syncthreads();
    gemv256w(v0, P.Wo, P.bo, 0, v1, red);
    gemv256w(v1, P.ro_W1, P.ro_b1, 1, v2, red);

    {   // logits: N=128; lane l -> outputs 2l,2l+1; wave w -> K quarter
        float2 acc = {0.f, 0.f};
        const float* Wp = P.ro_W2 + (size_t)(w * 64) * NR + l * 2;
        const float* xp = v2 + w * 64;
#pragma unroll 8
        for (int kk = 0; kk < 64; ++kk) {
            float xv = xp[kk];
            float2 wv = *(const float2*)(Wp + (size_t)kk * NR);
            acc.x += xv * wv.x; acc.y += xv * wv.y;
        }
        *(float2*)&red[w * 128 + l * 2] = acc;
        __syncthreads();
    }
    float logit = -1e30f;
    if (t < NR) logit = red[t] + red[128 + t] + red[256 + t] + red[384 + t] + P.ro_b2[t];
    __syncthreads();
    float m = logit;
#pragma unroll
    for (int off = 32; off; off >>= 1) m = fmaxf(m, __shfl_xor(m, off));
    if (l == 0) red[w] = m;
    __syncthreads();
    m = fmaxf(red[0], red[1]);
    float e = (t < NR) ? expf(logit - m) : 0.0f;
    float ssum = e;
#pragma unroll
    for (int off = 32; off; off >>= 1) ssum += __shfl_xor(ssum, off);
    if (l == 0) red[4 + w] = ssum;
    __syncthreads();
    float tot = red[4] + red[5];
    if (t < NR) P.out[b * NR + t] = e / tot;
}

// ---------------------------------------------------------------------------
extern "C" void kernel_launch(void* const* d_in, const int* in_sizes, int n_in,
                              void* d_out, int out_size, void* d_ws, size_t ws_size,
                              hipStream_t stream)
{
    KP P;
    P.x        = (const float*)d_in[0];
    P.We       = (const float*)d_in[1];
    P.be       = (const float*)d_in[2];
    P.msg_W1   = (const float*)d_in[3];
    P.msg_b1   = (const float*)d_in[4];
    P.msg_W2   = (const float*)d_in[5];
    P.msg_b2   = (const float*)d_in[6];
    P.upd_W1   = (const float*)d_in[7];
    P.upd_b1   = (const float*)d_in[8];
    P.upd_W2   = (const float*)d_in[9];
    P.upd_b2   = (const float*)d_in[10];
    P.ln_g     = (const float*)d_in[11];
    P.ln_b     = (const float*)d_in[12];
    P.rule_adj = (const float*)d_in[13];
    P.Wq       = (const float*)d_in[14];
    P.bq       = (const float*)d_in[15];
    P.Wk       = (const float*)d_in[16];
    P.bk       = (const float*)d_in[17];
    P.Wv       = (const float*)d_in[18];
    P.bv       = (const float*)d_in[19];
    P.Wo       = (const float*)d_in[20];
    P.bo       = (const float*)d_in[21];
    P.ro_W1    = (const float*)d_in[22];
    P.ro_b1    = (const float*)d_in[23];
    P.ro_W2    = (const float*)d_in[24];
    P.ro_b2    = (const float*)d_in[25];
    P.out      = (float*)d_out;

    float* b0 = (float*)d_ws;
    P.N0     = b0;  b0 += SZ;
    P.N1     = b0;  b0 += SZ;
    P.N2     = b0;  b0 += SZ;
    P.aB     = b0;  b0 += SZ;
    P.bbB    = b0;  b0 += SZ;
    P.p1B    = b0;  b0 += SZ;
    P.aA     = b0;  b0 += SZ;
    P.bbA    = b0;  b0 += SZ;
    P.p1A    = b0;  b0 += SZ;
    P.W2u    = b0;  b0 += 3 * HID * HID;
    P.mb2u   = b0;  b0 += 3 * HID;
    P.mW1s   = b0;  b0 += HID * HID;
    P.Aw     = b0;  b0 += NR * NR;
    P.rsum   = b0;  b0 += NR;
    P.h0g    = b0;  b0 += NB * HID;
    P.c0g    = b0;  b0 += NB * HID;
    P.c1g    = b0;  b0 += NB * HID;
    P.gacc   = b0;  b0 += NB * HID;
    P.scratch= b0;  b0 += 256;

    // 1. setup: adj | W2u (3 layers) | mb2u | h0 | mW1s | prefetch
    setup0_kernel<<<dim3(256), 256, 0, stream>>>(P);

    // 2. head chain fused: c0 || (p0 -> c1)
    headc_kernel<<<dim3(128), 256, 0, stream>>>(P);

    // 3. layer 0 + projection to layer-1 inputs (set B)
    layer0p_kernel<<<dim3(256), 512, 0, stream>>>(P);

    // 4. layer 1: agg + resid + LN + projection to layer-2 inputs (set A)
    {
        const int l = 1;
        const float* mW1a2 = P.msg_W1 + (size_t)2 * 2 * HID * HID;
        const float* uW1a2 = P.upd_W1 + (size_t)2 * 2 * HID * HID;
        aggproj_kernel<<<dim3(256), 512, 0, stream>>>(
            P.aB, P.bbB, P.msg_b1 + (size_t)l * HID, P.Aw, P.rsum,
            P.p1B, P.W2u + (size_t)l * HID * HID, P.mb2u + l * HID,
            P.upd_b1 + (size_t)l * HID,
            P.upd_W2 + (size_t)l * HID * HID, P.upd_b2 + (size_t)l * HID,
            P.N0, P.ln_g + (size_t)l * HID, P.ln_b + (size_t)l * HID, P.N1,
            mW1a2, nullptr, P.aA,
            mW1a2 + (size_t)HID * HID, nullptr, P.bbA,
            uW1a2, nullptr, P.p1A,
            nullptr);
    }

    // 5. layer 2: agg + resid + LN + projection to q/k/v (set B)
    {
        const int l = 2;
        aggproj_kernel<<<dim3(256), 512, 0, stream>>>(
            P.aA, P.bbA, P.msg_b1 + (size_t)l * HID, P.Aw, P.rsum,
            P.p1A, P.W2u + (size_t)l * HID * HID, P.mb2u + l * HID,
            P.upd_b1 + (size_t)l * HID,
            P.upd_W2 + (size_t)l * HID * HID, P.upd_b2 + (size_t)l * HID,
            P.N1, P.ln_g + (size_t)l * HID, P.ln_b + (size_t)l * HID, P.N2,
            P.Wq, P.bq, P.aB,
            P.Wk, P.bk, P.bbB,
            P.Wv, P.bv, P.p1B,
            P.gacc);
    }

    // 6. attention + mean (atomic into gacc)
    attention_kernel<<<dim3(256), 256, 0, stream>>>(P.aB, P.bbB, P.p1B, P.gacc);

    // 7. fused tail
    tailf_kernel<<<dim3(8), 256, 0, stream>>>(P);
}

// Round 10
// 231.774 us; speedup vs baseline: 1.2644x; 1.1158x over previous
//
#include <hip/hip_runtime.h>
#include <math.h>

// Problem dims (fixed)
constexpr int NB  = 8;    // batch
constexpr int NR  = 128;  // rule nodes
constexpr int HID = 256;  // hidden
constexpr int NIN = 512;  // input dim
constexpr int DHD = 64;   // head dim
constexpr size_t SZ = (size_t)NB * NR * HID;  // 262144

struct KP {
    const float *x, *We, *be, *msg_W1, *msg_b1, *msg_W2, *msg_b2;
    const float *upd_W1, *upd_b1, *upd_W2, *upd_b2, *ln_g, *ln_b, *rule_adj;
    const float *Wq, *bq, *Wk, *bk, *Wv, *bv, *Wo, *bo, *ro_W1, *ro_b1, *ro_W2, *ro_b2;
    float* out;
    float *N0, *N1, *N2;                 // normalized h streams
    float *aB, *bbB, *p1B;               // proj set B (layer inputs / qkv)
    float *aA, *bbA, *p1A;               // proj set A
    float *W2u, *mb2u, *Aw, *rsum;       // W2u[l] = msg_W2[l]@upd_W1b[l]
    float *mW1s;                         // layer0: msg_W1a + msg_W1b
    float *h0g;
    float *gacc;                         // tail mean accumulator [8,256]
    float *scratch;
};

// ---------------------------------------------------------------------------
// 64x64-tile fp32 GEMM core (K=256, BK=16) — used only in setup (W2u).
// ---------------------------------------------------------------------------
__device__ __forceinline__ void gemm_core(
    float (&As)[16][68], float (&Bs)[16][64], int m0, int n0,
    const float* __restrict__ A, const float* __restrict__ B,
    float (&acc)[4][4])
{
    int tid = threadIdx.x;
    int ty = tid >> 4, tx = tid & 15;
    int arow = tid >> 2, acol = (tid & 3) << 2;
    int brow = tid >> 4, bcol = (tid & 15) << 2;
    int m = m0 + arow;

    float4 av = *(const float4*)&A[(size_t)m * HID + acol];
    float4 bv = *(const float4*)&B[(size_t)brow * HID + n0 + bcol];

    for (int k0 = 0; k0 < HID; k0 += 16) {
        As[acol + 0][arow] = av.x;
        As[acol + 1][arow] = av.y;
        As[acol + 2][arow] = av.z;
        As[acol + 3][arow] = av.w;
        *(float4*)&Bs[brow][bcol] = bv;
        __syncthreads();
        if (k0 + 16 < HID) {
            av = *(const float4*)&A[(size_t)m * HID + k0 + 16 + acol];
            bv = *(const float4*)&B[(size_t)(k0 + 16 + brow) * HID + n0 + bcol];
        }
#pragma unroll
        for (int kk = 0; kk < 16; ++kk) {
            float4 af = *(const float4*)&As[kk][ty << 2];
            float4 bf = *(const float4*)&Bs[kk][tx << 2];
            float a_[4] = {af.x, af.y, af.z, af.w};
            float b_[4] = {bf.x, bf.y, bf.z, bf.w};
#pragma unroll
            for (int i = 0; i < 4; ++i)
#pragma unroll
                for (int j = 0; j < 4; ++j) acc[i][j] += a_[i] * b_[j];
        }
        __syncthreads();
    }
}

// ---------------------------------------------------------------------------
// Wave-split GEMV (tail): y[0..255] = act(xs @ W + bias). W row-major [256,256].
// ---------------------------------------------------------------------------
__device__ __forceinline__ void gemv256w(
    const float* xs, const float* __restrict__ W,
    const float* __restrict__ bias, int relu, float* ys, float* red)
{
    int tid = threadIdx.x;
    int w = tid >> 6, l = tid & 63;
    float4 acc = {0.f, 0.f, 0.f, 0.f};
    const float* Wp = W + (size_t)(w * 64) * HID + l * 4;
    const float* xp = xs + w * 64;
#pragma unroll 16
    for (int kk = 0; kk < 64; ++kk) {
        float xv = xp[kk];
        float4 wv = *(const float4*)(Wp + (size_t)kk * HID);
        acc.x += xv * wv.x; acc.y += xv * wv.y;
        acc.z += xv * wv.z; acc.w += xv * wv.w;
    }
    *(float4*)&red[w * 256 + l * 4] = acc;
    __syncthreads();
    float v = red[tid] + red[256 + tid] + red[512 + tid] + red[768 + tid];
    if (bias) v += bias[tid];
    if (relu) v = fmaxf(v, 0.0f);
    ys[tid] = v;
    __syncthreads();
}

// ---------------------------------------------------------------------------
// k-quarter partial of rows4 matmul: col in [0,256), q in [0,4).
// o[ii] = sum over k in [q*64, q*64+64) of rows[ii][k] * W[k][col].
// ---------------------------------------------------------------------------
__device__ __forceinline__ void rows4_q(
    const float (&rows)[4][HID], const float* __restrict__ W,
    int col, int q, float o[4])
{
    o[0] = o[1] = o[2] = o[3] = 0.f;
    int kb = q * 64;
#pragma unroll 4
    for (int k0 = 0; k0 < 64; k0 += 4) {
        int k = kb + k0;
        float w0 = W[(size_t)(k + 0) * HID + col];
        float w1 = W[(size_t)(k + 1) * HID + col];
        float w2 = W[(size_t)(k + 2) * HID + col];
        float w3 = W[(size_t)(k + 3) * HID + col];
#pragma unroll
        for (int ii = 0; ii < 4; ++ii) {
            float4 rv = *(const float4*)&rows[ii][k];
            o[ii] += rv.x * w0 + rv.y * w1 + rv.z * w2 + rv.w * w3;
        }
    }
}

// Single-row k-quarter GEMV partial.
__device__ __forceinline__ float gemv_q(
    const float* xs, const float* __restrict__ W, int col, int q)
{
    float o = 0.f;
    int kb = q * 64;
#pragma unroll 8
    for (int k = 0; k < 64; ++k)
        o += xs[kb + k] * W[(size_t)(kb + k) * HID + col];
    return o;
}

// LN stats over quarter-0 threads (cols 0..255); mu/inv -> mi[4][2].
__device__ __forceinline__ void ln_stats4_q(
    float (&sred)[4][4][2], float (&mi)[4][2], const float v[4], int q)
{
    if (q == 0) {
        int w = threadIdx.x >> 6, l = threadIdx.x & 63;
        float s[4], qq[4];
#pragma unroll
        for (int ii = 0; ii < 4; ++ii) { s[ii] = v[ii]; qq[ii] = v[ii] * v[ii]; }
#pragma unroll
        for (int off = 32; off; off >>= 1) {
#pragma unroll
            for (int ii = 0; ii < 4; ++ii) {
                s[ii] += __shfl_xor(s[ii], off);
                qq[ii] += __shfl_xor(qq[ii], off);
            }
        }
        if (l == 0) {
#pragma unroll
            for (int ii = 0; ii < 4; ++ii) { sred[w][ii][0] = s[ii]; sred[w][ii][1] = qq[ii]; }
        }
    }
    __syncthreads();
    if (threadIdx.x < 4) {
        int r = threadIdx.x;
        float ss = sred[0][r][0] + sred[1][r][0] + sred[2][r][0] + sred[3][r][0];
        float qq = sred[0][r][1] + sred[1][r][1] + sred[2][r][1] + sred[3][r][1];
        float mu = ss * (1.0f / HID);
        mi[r][0] = mu;
        mi[r][1] = rsqrtf(qq * (1.0f / HID) - mu * mu + 1e-5f);
    }
    __syncthreads();
}

// ---------------------------------------------------------------------------
// Setup: adjacency | W2u[l]=mW2[l]@uW1b[l] | mb2u | h0 | mW1s | prefetch.
// ---------------------------------------------------------------------------
__global__ __launch_bounds__(256) void setup0_kernel(KP P) {
    __shared__ union {
        struct { float As[16][68]; float Bs[16][64]; } g;
        struct { float xs[NIN]; float part[8][32]; } e;
    } L;
    int blk = blockIdx.x;
    int t = threadIdx.x;

    if (blk < 32) {
        int rr = blk * 4 + (t >> 6);
        int l = t & 63;
        float s_loc = 0.f;
#pragma unroll
        for (int rep = 0; rep < 2; ++rep) {
            int j = l + rep * 64;
            float xv = P.rule_adj[rr * NR + j];
            float sg = 1.0f / (1.0f + expf(-xv));
            if (j == rr) sg = 0.0f;
            P.Aw[rr * NR + j] = sg;
            s_loc += sg;
        }
#pragma unroll
        for (int off = 32; off; off >>= 1) s_loc += __shfl_xor(s_loc, off);
        if (l == 0) P.rsum[rr] = s_loc;
    } else if (blk < 80) {
        int idx = blk - 32, l2 = idx >> 4, t16 = idx & 15;
        int m0 = (t16 >> 2) * 64, n0 = (t16 & 3) * 64;
        float acc[4][4] = {};
        gemm_core(L.g.As, L.g.Bs, m0, n0,
                  P.msg_W2 + (size_t)l2 * HID * HID,
                  P.upd_W1 + (size_t)l2 * 2 * HID * HID + (size_t)HID * HID,
                  acc);
        int ty = t >> 4, tx = t & 15;
        float* C = P.W2u + (size_t)l2 * HID * HID;
#pragma unroll
        for (int i = 0; i < 4; ++i) {
            int m = m0 + (ty << 2) + i, n = n0 + (tx << 2);
            float4 o = {acc[i][0], acc[i][1], acc[i][2], acc[i][3]};
            *(float4*)&C[(size_t)m * HID + n] = o;
        }
    } else if (blk < 83) {
        int l2 = blk - 80;
        const float* b2v = P.msg_b2 + l2 * HID;
        const float* Bm = P.upd_W1 + (size_t)l2 * 2 * HID * HID + (size_t)HID * HID;
        float acc = 0.f;
#pragma unroll 4
        for (int k = 0; k < HID; ++k) acc += b2v[k] * Bm[(size_t)k * HID + t];
        P.mb2u[l2 * HID + t] = acc;
    } else if (blk < 147) {
        // h0[b] = x[b]@We + be, distributed (8 b x 8 col-slices)
        int idx = blk - 83;
        int b = idx >> 3, s = idx & 7;
        L.e.xs[t]       = P.x[b * NIN + t];
        L.e.xs[256 + t] = P.x[b * NIN + 256 + t];
        __syncthreads();
        int c = t & 31, seg = t >> 5;
        int col = s * 32 + c;
        const float* Wp = P.We + (size_t)(seg * 64) * HID + col;
        const float* xp = L.e.xs + seg * 64;
        float acc = 0.f;
#pragma unroll 16
        for (int k = 0; k < 64; ++k) acc += xp[k] * Wp[(size_t)k * HID];
        L.e.part[seg][c] = acc;
        __syncthreads();
        if (t < 32) {
            float v = 0.f;
#pragma unroll
            for (int sg = 0; sg < 8; ++sg) v += L.e.part[sg][t];
            int cc = s * 32 + t;
            P.h0g[b * HID + cc] = v + P.be[cc];
        }
    } else if (blk < 163) {
        int base = (blk - 147) * 4096;
        for (int i = t; i < 4096; i += 256) {
            int o = base + i;
            P.mW1s[o] = P.msg_W1[o] + P.msg_W1[65536 + o];
        }
    } else {
        // prefetch all weights -> warm L3 (poison evicts it every replay)
        int pfid = blk - 163, npf = 256 - 163;
        const float* arr[11] = {P.We, P.msg_W1, P.msg_W2, P.upd_W1, P.upd_W2,
                                P.Wq, P.Wk, P.Wv, P.Wo, P.ro_W1, P.ro_W2};
        const int n4[11] = {32768, 98304, 49152, 98304, 49152,
                            16384, 16384, 16384, 16384, 16384, 8192};
        float s = 0.f;
        for (int a = 0; a < 11; ++a) {
            const float4* p4 = (const float4*)arr[a];
            for (int i = pfid * 256 + t; i < n4[a]; i += npf * 256) {
                float4 v = p4[i];
                s += v.x + v.y + v.z + v.w;
            }
        }
        if (s == 1.0e37f) P.scratch[pfid] = s;  // keeps loads live
    }
}

// ---------------------------------------------------------------------------
// Layer 0 + head chain + projection. 1024 threads (col, k-quarter),
// grid 256 (4 rows/block). Head GEMVs (c0,p0,c1) computed per block
// (redundant across the 32 blocks of a batch, but each stage is only
// 64 MACs/thread).
// ---------------------------------------------------------------------------
__global__ __launch_bounds__(1024) void layer0p_kernel(KP P) {
    __shared__ float h0s[HID], p0s[HID], c0s[HID], c1s[HID];
    __shared__ float u1s[4][HID];
    __shared__ float nrm[4][HID];
    __shared__ float part4[4][4][HID];
    __shared__ float sred[4][4][2];
    __shared__ float mi[4][2];
    int blk = blockIdx.x;
    int m0 = blk * 4;
    int b = m0 >> 7, i0 = m0 & 127;
    int t = threadIdx.x;
    int col = t & 255, q = t >> 8;

    if (q == 0) h0s[col] = P.h0g[b * HID + col];
    __syncthreads();

    // head: c0 = h0@uW1a(0), p0 = relu(h0@mW1s + mb1(0))  (both k-quartered)
    part4[q][0][col] = gemv_q(h0s, P.upd_W1, col, q);
    part4[q][1][col] = gemv_q(h0s, P.mW1s, col, q);
    __syncthreads();
    if (q == 0) {
        c0s[col] = part4[0][0][col] + part4[1][0][col] + part4[2][0][col] + part4[3][0][col];
        float pv = part4[0][1][col] + part4[1][1][col] + part4[2][1][col] + part4[3][1][col];
        p0s[col] = fmaxf(pv + P.msg_b1[col], 0.0f);
    }
    __syncthreads();
    // c1 = p0@W2u(0) + mb2u(0)
    part4[q][0][col] = gemv_q(p0s, P.W2u, col, q);
    __syncthreads();
    if (q == 0) {
        c1s[col] = part4[0][0][col] + part4[1][0][col] + part4[2][0][col] + part4[3][0][col]
                 + P.mb2u[col];
        // u1 rows
        float ubv = P.upd_b1[col];
#pragma unroll
        for (int ii = 0; ii < 4; ++ii)
            u1s[ii][col] = fmaxf(c0s[col] + P.rsum[i0 + ii] * c1s[col] + ubv, 0.0f);
    }
    __syncthreads();

    // u = u1s@uW2(0); v = h0 + u + ub2(0); LN -> nrm, N0
    float o[4];
    rows4_q(u1s, P.upd_W2, col, q, o);
#pragma unroll
    for (int ii = 0; ii < 4; ++ii) part4[q][ii][col] = o[ii];
    __syncthreads();
    float v[4] = {0.f, 0.f, 0.f, 0.f};
    if (q == 0) {
        float h0v = h0s[col] + P.upd_b2[col];
#pragma unroll
        for (int ii = 0; ii < 4; ++ii)
            v[ii] = part4[0][ii][col] + part4[1][ii][col] + part4[2][ii][col]
                  + part4[3][ii][col] + h0v;
    }
    ln_stats4_q(sred, mi, v, q);
    if (q == 0) {
        float gv = P.ln_g[col], btv = P.ln_b[col];
#pragma unroll
        for (int ii = 0; ii < 4; ++ii) {
            float nv = (v[ii] - mi[ii][0]) * mi[ii][1] * gv + btv;
            nrm[ii][col] = nv;
            P.N0[(size_t)(m0 + ii) * HID + col] = nv;
        }
    }
    __syncthreads();

    // projections to layer-1 inputs
    const float* mW1a1 = P.msg_W1 + (size_t)1 * 2 * HID * HID;
    const float* uW1a1 = P.upd_W1 + (size_t)1 * 2 * HID * HID;
    const float* pw[3] = {mW1a1, mW1a1 + (size_t)HID * HID, uW1a1};
    float* po[3] = {P.aB, P.bbB, P.p1B};
#pragma unroll
    for (int p = 0; p < 3; ++p) {
        rows4_q(nrm, pw[p], col, q, o);
#pragma unroll
        for (int ii = 0; ii < 4; ++ii) part4[q][ii][col] = o[ii];
        __syncthreads();
        if (q == 0) {
#pragma unroll
            for (int ii = 0; ii < 4; ++ii)
                po[p][(size_t)(m0 + ii) * HID + col] =
                    part4[0][ii][col] + part4[1][ii][col] +
                    part4[2][ii][col] + part4[3][ii][col];
        }
        __syncthreads();
    }
}

// ---------------------------------------------------------------------------
// Fused aggregate + u1 + resid + LN + next-layer projection.
// 1024 threads (col, quarter), grid 256 (4 rows/block). j- and k-quartered.
// ---------------------------------------------------------------------------
__global__ __launch_bounds__(1024) void aggproj_kernel(
    const float* __restrict__ a, const float* __restrict__ bbv,
    const float* __restrict__ mb1, const float* __restrict__ Aw,
    const float* __restrict__ rsumv,
    const float* __restrict__ P1, const float* __restrict__ W2u,
    const float* __restrict__ mb2u, const float* __restrict__ ub1,
    const float* __restrict__ uW2, const float* __restrict__ ub2,
    const float* __restrict__ Nprev, const float* __restrict__ lng,
    const float* __restrict__ lnb, float* __restrict__ Nout,
    const float* __restrict__ pw0, const float* __restrict__ pb0, float* __restrict__ o0,
    const float* __restrict__ pw1, const float* __restrict__ pb1, float* __restrict__ o1,
    const float* __restrict__ pw2, const float* __restrict__ pb2, float* __restrict__ o2,
    float* __restrict__ gzero)
{
    __shared__ float ap[4][HID];
    __shared__ float u1s[4][HID];
    __shared__ float nrm[4][HID];
    __shared__ float awr[4][NR];
    __shared__ float part4[4][4][HID];
    __shared__ float sred[4][4][2];
    __shared__ float mi[4][2];
    int blk = blockIdx.x;
    int b  = blk >> 5;
    int i0 = (blk & 31) * 4;
    int m0 = b * NR + i0;
    int t  = threadIdx.x;
    int col = t & 255, q = t >> 8;

    if (gzero && blk == 0 && q == 0) {
#pragma unroll
        for (int i = 0; i < 8; ++i) gzero[i * 256 + col] = 0.f;
    }

    // stage adjacency rows: threads 0..511 cover 4x128
    if (t < 512) awr[t >> 7][t & 127] = Aw[(i0 + (t >> 7)) * NR + (t & 127)];

    float bias = mb1[col];
    float ai[4];
#pragma unroll
    for (int ii = 0; ii < 4; ++ii)
        ai[ii] = a[(size_t)(m0 + ii) * HID + col] + bias;
    __syncthreads();

    // aggregate, j-quarter: q sums j in [q*32, q*32+32)
    {
        float acc[4] = {0.f, 0.f, 0.f, 0.f};
        const float* bbb = &bbv[(size_t)b * NR * HID + col];
        int jb = q * 32;
#pragma unroll 4
        for (int j = 0; j < 32; ++j) {
            float bj = bbb[(size_t)(jb + j) * HID];
#pragma unroll
            for (int ii = 0; ii < 4; ++ii) {
                float pre = fmaxf(ai[ii] + bj, 0.0f);
                acc[ii] += awr[ii][jb + j] * pre;
            }
        }
#pragma unroll
        for (int ii = 0; ii < 4; ++ii) part4[q][ii][col] = acc[ii];
        __syncthreads();
        if (q == 0) {
#pragma unroll
            for (int ii = 0; ii < 4; ++ii)
                ap[ii][col] = part4[0][ii][col] + part4[1][ii][col]
                            + part4[2][ii][col] + part4[3][ii][col];
        }
        __syncthreads();
    }

    // u1 = relu(ap@W2u + P1 + rsum*mb2u + ub1)   (k-quartered)
    {
        float o[4];
        rows4_q(ap, W2u, col, q, o);
#pragma unroll
        for (int ii = 0; ii < 4; ++ii) part4[q][ii][col] = o[ii];
        __syncthreads();
        if (q == 0) {
            float mbv = mb2u[col], ubv = ub1[col];
#pragma unroll
            for (int ii = 0; ii < 4; ++ii) {
                float w2f = part4[0][ii][col] + part4[1][ii][col]
                          + part4[2][ii][col] + part4[3][ii][col];
                float vv = w2f + P1[(size_t)(m0 + ii) * HID + col]
                         + rsumv[i0 + ii] * mbv + ubv;
                u1s[ii][col] = fmaxf(vv, 0.0f);
            }
        }
        __syncthreads();
    }

    // u = u1s@uW2 ; v = Nprev + u + ub2 ; LN -> nrm, Nout
    {
        float o[4];
        rows4_q(u1s, uW2, col, q, o);
#pragma unroll
        for (int ii = 0; ii < 4; ++ii) part4[q][ii][col] = o[ii];
        __syncthreads();
        float v[4] = {0.f, 0.f, 0.f, 0.f};
        if (q == 0) {
            float ub2v = ub2[col];
#pragma unroll
            for (int ii = 0; ii < 4; ++ii) {
                float uf = part4[0][ii][col] + part4[1][ii][col]
                         + part4[2][ii][col] + part4[3][ii][col];
                v[ii] = Nprev[(size_t)(m0 + ii) * HID + col] + uf + ub2v;
            }
        }
        ln_stats4_q(sred, mi, v, q);
        if (q == 0) {
            float gv = lng[col], btv = lnb[col];
#pragma unroll
            for (int ii = 0; ii < 4; ++ii) {
                float nv = (v[ii] - mi[ii][0]) * mi[ii][1] * gv + btv;
                nrm[ii][col] = nv;
                Nout[(size_t)(m0 + ii) * HID + col] = nv;
            }
        }
        __syncthreads();
    }

    // three projections (k-quartered)
    {
        const float* pw[3] = {pw0, pw1, pw2};
        const float* pb[3] = {pb0, pb1, pb2};
        float* po[3] = {o0, o1, o2};
#pragma unroll
        for (int p = 0; p < 3; ++p) {
            float o[4];
            rows4_q(nrm, pw[p], col, q, o);
#pragma unroll
            for (int ii = 0; ii < 4; ++ii) part4[q][ii][col] = o[ii];
            __syncthreads();
            if (q == 0) {
                float pbv = pb[p] ? pb[p][col] : 0.f;
#pragma unroll
                for (int ii = 0; ii < 4; ++ii)
                    po[p][(size_t)(m0 + ii) * HID + col] =
                        part4[0][ii][col] + part4[1][ii][col] +
                        part4[2][ii][col] + part4[3][ii][col] + pbv;
            }
            __syncthreads();
        }
    }
}

// ---------------------------------------------------------------------------
// Fused attention + mean: blk = bh*8 + ig; 16 q-rows per block, one (b,head).
// ---------------------------------------------------------------------------
__global__ __launch_bounds__(256) void attention_kernel(
    const float* __restrict__ q, const float* __restrict__ k,
    const float* __restrict__ v, float* __restrict__ gacc)
{
    __shared__ struct { float KhT[64][128]; float S[16][128]; float qs[16][64]; } L;
    int blk = blockIdx.x;
    int bh = blk >> 3, ig = blk & 7;
    int b = bh >> 2, hd = bh & 3;
    int i0 = ig * 16;
    int t = threadIdx.x;
    const float* qg = q + ((size_t)b * NR) * HID + hd * DHD;
    const float* kg = k + ((size_t)b * NR) * HID + hd * DHD;
    const float* vg = v + ((size_t)b * NR) * HID + hd * DHD;

    {   // stage K^T
        int j = t >> 1, half = t & 1;
        const float* krow = kg + (size_t)j * HID + half * 32;
#pragma unroll
        for (int c = 0; c < 32; c += 4) {
            float4 kv = *(const float4*)(krow + c);
            L.KhT[half * 32 + c + 0][j] = kv.x;
            L.KhT[half * 32 + c + 1][j] = kv.y;
            L.KhT[half * 32 + c + 2][j] = kv.z;
            L.KhT[half * 32 + c + 3][j] = kv.w;
        }
    }
    {   // stage q rows
        int ii = t >> 4, d0 = (t & 15) * 4;
        *(float4*)&L.qs[ii][d0] = *(const float4*)(qg + (size_t)(i0 + ii) * HID + d0);
    }
    __syncthreads();
    {   // scores
        int j = t & 127, ii2 = t >> 7;
        float acc[8] = {0.f,0.f,0.f,0.f,0.f,0.f,0.f,0.f};
#pragma unroll 4
        for (int d = 0; d < 64; ++d) {
            float kv = L.KhT[d][j];
#pragma unroll
            for (int ii = 0; ii < 8; ++ii) acc[ii] += L.qs[ii2 * 8 + ii][d] * kv;
        }
#pragma unroll
        for (int ii = 0; ii < 8; ++ii) L.S[ii2 * 8 + ii][j] = acc[ii] * 0.125f;
    }
    __syncthreads();
    {   // softmax per row
        int w = t >> 6, l = t & 63;
#pragma unroll
        for (int r = w * 4; r < w * 4 + 4; ++r) {
            float e0 = L.S[r][l], e1 = L.S[r][l + 64];
            float mx = fmaxf(e0, e1);
#pragma unroll
            for (int off = 32; off; off >>= 1) mx = fmaxf(mx, __shfl_xor(mx, off));
            e0 = expf(e0 - mx); e1 = expf(e1 - mx);
            float sm = e0 + e1;
#pragma unroll
            for (int off = 32; off; off >>= 1) sm += __shfl_xor(sm, off);
            float inv = 1.0f / sm;
            L.S[r][l] = e0 * inv; L.S[r][l + 64] = e1 * inv;
        }
    }
    __syncthreads();
    {   // PV + row-sum into gacc
        int d = t & 63, ir = t >> 6;
        float accv[4] = {0.f, 0.f, 0.f, 0.f};
        const float* vp = vg + d;
#pragma unroll 8
        for (int j = 0; j < NR; ++j) {
            float vv = vp[(size_t)j * HID];
#pragma unroll
            for (int p = 0; p < 4; ++p) accv[p] += L.S[p * 4 + ir][j] * vv;
        }
        float s = accv[0] + accv[1] + accv[2] + accv[3];
        atomicAdd(&gacc[b * HID + hd * DHD + d], s);
    }
}

// ---------------------------------------------------------------------------
// Fused tail: per-batch chain. 8 blocks.
// ---------------------------------------------------------------------------
__global__ __launch_bounds__(256) void tailf_kernel(KP P) {
    __shared__ float v0[HID], v1[HID], v2[HID];
    __shared__ float red[1024];
    int b = blockIdx.x;
    int t = threadIdx.x;
    int w = t >> 6, l = t & 63;

    v0[t] = P.gacc[b * HID + t] * (1.0f / NR);
    __syncthreads();
    gemv256w(v0, P.Wo, P.bo, 0, v1, red);
    gemv256w(v1, P.ro_W1, P.ro_b1, 1, v2, red);

    {   // logits: N=128; lane l -> outputs 2l,2l+1; wave w -> K quarter
        float2 acc = {0.f, 0.f};
        const float* Wp = P.ro_W2 + (size_t)(w * 64) * NR + l * 2;
        const float* xp = v2 + w * 64;
#pragma unroll 8
        for (int kk = 0; kk < 64; ++kk) {
            float xv = xp[kk];
            float2 wv = *(const float2*)(Wp + (size_t)kk * NR);
            acc.x += xv * wv.x; acc.y += xv * wv.y;
        }
        *(float2*)&red[w * 128 + l * 2] = acc;
        __syncthreads();
    }
    float logit = -1e30f;
    if (t < NR) logit = red[t] + red[128 + t] + red[256 + t] + red[384 + t] + P.ro_b2[t];
    __syncthreads();
    float m = logit;
#pragma unroll
    for (int off = 32; off; off >>= 1) m = fmaxf(m, __shfl_xor(m, off));
    if (l == 0) red[w] = m;
    __syncthreads();
    m = fmaxf(red[0], red[1]);
    float e = (t < NR) ? expf(logit - m) : 0.0f;
    float ssum = e;
#pragma unroll
    for (int off = 32; off; off >>= 1) ssum += __shfl_xor(ssum, off);
    if (l == 0) red[4 + w] = ssum;
    __syncthreads();
    float tot = red[4] + red[5];
    if (t < NR) P.out[b * NR + t] = e / tot;
}

// ---------------------------------------------------------------------------
extern "C" void kernel_launch(void* const* d_in, const int* in_sizes, int n_in,
                              void* d_out, int out_size, void* d_ws, size_t ws_size,
                              hipStream_t stream)
{
    KP P;
    P.x        = (const float*)d_in[0];
    P.We       = (const float*)d_in[1];
    P.be       = (const float*)d_in[2];
    P.msg_W1   = (const float*)d_in[3];
    P.msg_b1   = (const float*)d_in[4];
    P.msg_W2   = (const float*)d_in[5];
    P.msg_b2   = (const float*)d_in[6];
    P.upd_W1   = (const float*)d_in[7];
    P.upd_b1   = (const float*)d_in[8];
    P.upd_W2   = (const float*)d_in[9];
    P.upd_b2   = (const float*)d_in[10];
    P.ln_g     = (const float*)d_in[11];
    P.ln_b     = (const float*)d_in[12];
    P.rule_adj = (const float*)d_in[13];
    P.Wq       = (const float*)d_in[14];
    P.bq       = (const float*)d_in[15];
    P.Wk       = (const float*)d_in[16];
    P.bk       = (const float*)d_in[17];
    P.Wv       = (const float*)d_in[18];
    P.bv       = (const float*)d_in[19];
    P.Wo       = (const float*)d_in[20];
    P.bo       = (const float*)d_in[21];
    P.ro_W1    = (const float*)d_in[22];
    P.ro_b1    = (const float*)d_in[23];
    P.ro_W2    = (const float*)d_in[24];
    P.ro_b2    = (const float*)d_in[25];
    P.out      = (float*)d_out;

    float* b0 = (float*)d_ws;
    P.N0     = b0;  b0 += SZ;
    P.N1     = b0;  b0 += SZ;
    P.N2     = b0;  b0 += SZ;
    P.aB     = b0;  b0 += SZ;
    P.bbB    = b0;  b0 += SZ;
    P.p1B    = b0;  b0 += SZ;
    P.aA     = b0;  b0 += SZ;
    P.bbA    = b0;  b0 += SZ;
    P.p1A    = b0;  b0 += SZ;
    P.W2u    = b0;  b0 += 3 * HID * HID;
    P.mb2u   = b0;  b0 += 3 * HID;
    P.mW1s   = b0;  b0 += HID * HID;
    P.Aw     = b0;  b0 += NR * NR;
    P.rsum   = b0;  b0 += NR;
    P.h0g    = b0;  b0 += NB * HID;
    P.gacc   = b0;  b0 += NB * HID;
    P.scratch= b0;  b0 += 256;

    // 1. setup: adj | W2u (3 layers) | mb2u | h0 | mW1s | prefetch
    setup0_kernel<<<dim3(256), 256, 0, stream>>>(P);

    // 2. layer 0 (+ head chain) + projection to layer-1 inputs (set B)
    layer0p_kernel<<<dim3(256), 1024, 0, stream>>>(P);

    // 3. layer 1: agg + resid + LN + projection to layer-2 inputs (set A)
    {
        const int l = 1;
        const float* mW1a2 = P.msg_W1 + (size_t)2 * 2 * HID * HID;
        const float* uW1a2 = P.upd_W1 + (size_t)2 * 2 * HID * HID;
        aggproj_kernel<<<dim3(256), 1024, 0, stream>>>(
            P.aB, P.bbB, P.msg_b1 + (size_t)l * HID, P.Aw, P.rsum,
            P.p1B, P.W2u + (size_t)l * HID * HID, P.mb2u + l * HID,
            P.upd_b1 + (size_t)l * HID,
            P.upd_W2 + (size_t)l * HID * HID, P.upd_b2 + (size_t)l * HID,
            P.N0, P.ln_g + (size_t)l * HID, P.ln_b + (size_t)l * HID, P.N1,
            mW1a2, nullptr, P.aA,
            mW1a2 + (size_t)HID * HID, nullptr, P.bbA,
            uW1a2, nullptr, P.p1A,
            nullptr);
    }

    // 4. layer 2: agg + resid + LN + projection to q/k/v (set B)
    {
        const int l = 2;
        aggproj_kernel<<<dim3(256), 1024, 0, stream>>>(
            P.aA, P.bbA, P.msg_b1 + (size_t)l * HID, P.Aw, P.rsum,
            P.p1A, P.W2u + (size_t)l * HID * HID, P.mb2u + l * HID,
            P.upd_b1 + (size_t)l * HID,
            P.upd_W2 + (size_t)l * HID * HID, P.upd_b2 + (size_t)l * HID,
            P.N1, P.ln_g + (size_t)l * HID, P.ln_b + (size_t)l * HID, P.N2,
            P.Wq, P.bq, P.aB,
            P.Wk, P.bk, P.bbB,
            P.Wv, P.bv, P.p1B,
            P.gacc);
    }

    // 5. attention + mean (atomic into gacc)
    attention_kernel<<<dim3(256), 256, 0, stream>>>(P.aB, P.bbB, P.p1B, P.gacc);

    // 6. fused tail
    tailf_kernel<<<dim3(8), 256, 0, stream>>>(P);
}